// Round 4
// baseline (712.303 us; speedup 1.0000x reference)
//
#include <hip/hip_runtime.h>
#include <math.h>

// DSSIM (mean), B=32 C=3 H=W=512 fp32, separable 11x11 Gaussian.
// R3: software-pipelined sliding ring.
//  - Block = 32-col strip, sweeps 512 rows in 8 chunks of 64.
//  - Steady state: exactly 1 h-task/thread/chunk; next chunk's raw windows
//    (2 x 6 x float4) held in REGISTERS, loads issued a full chunk ahead so
//    HBM latency overlaps the v-phase + barrier (was: 8 exposed stalls).
//  - Ring LDS (74 rows x 4 xg x 44 floats = 52 KB, 3 blocks/CU) carries the
//    v-halo; each raw row is read from global exactly once per strip.
//  - SSIM divide via v_rcp_f32 (rel err ~1e-7 << 9.9e-3 threshold).

namespace {
constexpr int IMG = 512;
constexpr int TW = 32;                 // strip width
constexpr int RB = 64;                 // output rows per chunk
constexpr int RING = RB + 10;          // 74 ring rows
constexpr int SLOT = 44;               // floats per (xg, ringrow) slot
constexpr int XGN = TW / 8;            // 4 col-groups
constexpr int NCHUNK = IMG / RB;       // 8
constexpr int CTILES = IMG / TW;       // 16 strips per image
constexpr int NIMG = 96;               // 32*3
constexpr float C1c = 1e-4f;
constexpr float C2c = 9e-4f;
constexpr float INV_N = 1.0f / 25165824.0f;  // 1/(96*512*512)
}

__global__ void dssim_zero(float* ws) { ws[0] = 0.0f; }

__global__ void dssim_final(const float* __restrict__ ws, float* __restrict__ out) {
  out[0] = ws[0] * INV_N;
}

__global__ __launch_bounds__(256, 3) void dssim_main(
    const float* __restrict__ im1, const float* __restrict__ im2,
    const float* __restrict__ gk, float* __restrict__ ws)
{
  __shared__ float sR[XGN * RING * SLOT];   // 52,096 B

  const int tid = threadIdx.x;
  const int bid = blockIdx.x;
  const int img = bid >> 4;
  const int tsx = bid & 15;
  const int X0s = tsx * TW;

  const float* __restrict__ p1 = im1 + (size_t)img * (IMG * IMG);
  const float* __restrict__ p2 = im2 + (size_t)img * (IMG * IMG);

  // k1[i] = k2d[i][5] / sqrt(k2d[5][5])  (separable, sum(k1)=1)
  float wt[11];
  {
    float ic = 1.0f / sqrtf(gk[5 * 11 + 5]);
    #pragma unroll
    for (int i = 0; i < 11; ++i) wt[i] = gk[i * 11 + 5] * ic;
  }

  // steady-state h mapping: 1 task per thread
  const int xg = tid & 3;
  const int dr = tid >> 2;               // 0..63
  const int cbf = X0s + xg * 8 - 8;
  const bool intf = (cbf >= 0) && (cbf + 24 <= IMG);

  // v-phase mapping
  const int c   = tid & 31;
  const int yg  = tid >> 5;
  const int xg3 = c >> 3;
  const int cl  = c & 7;

  auto loadrow = [&](const float* __restrict__ p, int r, int cbx, bool inter,
                     float4* dst) {
    const float* row = p + r * IMG;
    if (inter) {
      #pragma unroll
      for (int i = 0; i < 6; ++i) dst[i] = *(const float4*)(row + cbx + 4 * i);
    } else {
      #pragma unroll
      for (int i = 0; i < 6; ++i) {
        int c0 = cbx + 4 * i;
        float e0 = ((unsigned)(c0 + 0) < (unsigned)IMG) ? row[c0 + 0] : 0.f;
        float e1 = ((unsigned)(c0 + 1) < (unsigned)IMG) ? row[c0 + 1] : 0.f;
        float e2 = ((unsigned)(c0 + 2) < (unsigned)IMG) ? row[c0 + 2] : 0.f;
        float e3 = ((unsigned)(c0 + 3) < (unsigned)IMG) ? row[c0 + 3] : 0.f;
        dst[i] = make_float4(e0, e1, e2, e3);
      }
    }
  };

  // h-blur 5 quantities from register windows, write packed ring slot
  auto hcompute = [&](const float4* A, const float4* B, bool valid,
                      int xgw, int ringrow) {
    float a24[24], b24[24];
    #pragma unroll
    for (int i = 0; i < 6; ++i) {
      a24[4*i+0] = valid ? A[i].x : 0.f;  a24[4*i+1] = valid ? A[i].y : 0.f;
      a24[4*i+2] = valid ? A[i].z : 0.f;  a24[4*i+3] = valid ? A[i].w : 0.f;
      b24[4*i+0] = valid ? B[i].x : 0.f;  b24[4*i+1] = valid ? B[i].y : 0.f;
      b24[4*i+2] = valid ? B[i].z : 0.f;  b24[4*i+3] = valid ? B[i].w : 0.f;
    }
    float o0[8], o1[8], o2[8], o3[8], o4[8];
    #pragma unroll
    for (int j = 0; j < 8; ++j) { o0[j]=0.f; o1[j]=0.f; o2[j]=0.f; o3[j]=0.f; o4[j]=0.f; }
    #pragma unroll
    for (int e = 0; e < 18; ++e) {
      float va = a24[e + 3], vb = b24[e + 3];
      float pa = va * va, pb = vb * vb, pab = va * vb;
      #pragma unroll
      for (int j = 0; j < 8; ++j) {
        int kk = e - j;
        if (kk >= 0 && kk < 11) {
          float w = wt[kk];
          o0[j] = fmaf(w, va,  o0[j]);
          o1[j] = fmaf(w, vb,  o1[j]);
          o2[j] = fmaf(w, pa,  o2[j]);
          o3[j] = fmaf(w, pb,  o3[j]);
          o4[j] = fmaf(w, pab, o4[j]);
        }
      }
    }
    const int base = (xgw * RING + ringrow) * SLOT;
    #pragma unroll
    for (int j = 0; j < 8; ++j)
      *(float4*)&sR[base + 4 * j] = make_float4(o0[j], o1[j], o2[j], o3[j]);
    *(float4*)&sR[base + 32] = make_float4(o4[0], o4[1], o4[2], o4[3]);
    *(float4*)&sR[base + 36] = make_float4(o4[4], o4[5], o4[6], o4[7]);
  };

  // ---- startup: fill ring with h-rows -5..68 (296 tasks) ----
  for (int t = tid; t < XGN * RING; t += 256) {
    int sxg = t & 3, sdr = t >> 2;
    int r = sdr - 5;
    int scb = X0s + sxg * 8 - 8;
    bool sint = (scb >= 0) && (scb + 24 <= IMG);
    float4 LA[6], LB[6];
    bool valid = (unsigned)r < (unsigned)IMG;
    if (valid) { loadrow(p1, r, scb, sint, LA); loadrow(p2, r, scb, sint, LB); }
    hcompute(LA, LB, valid, sxg, r + 5);
  }

  // prefetch chunk-1 body rows (69..132) into registers
  float4 A[6], B[6];
  {
    int r = RB + 5 + dr;
    if ((unsigned)r < (unsigned)IMG) {
      loadrow(p1, r, cbf, intf, A);
      loadrow(p2, r, cbf, intf, B);
    }
  }
  __syncthreads();

  float lsum = 0.f;
  for (int k = 0; k < NCHUNK; ++k) {
    // ---- v-phase: 8 output rows per thread + SSIM ----
    float mu1[8], mu2[8], e11[8], e22[8], e12[8];
    #pragma unroll
    for (int j = 0; j < 8; ++j) { mu1[j]=0.f; mu2[j]=0.f; e11[j]=0.f; e22[j]=0.f; e12[j]=0.f; }

    const int rbase = (RB * k + yg * 8) % RING;
    #pragma unroll
    for (int rrr = 0; rrr < 18; ++rrr) {
      int idx = rbase + rrr;
      if (idx >= RING) idx -= RING;
      const int a = (xg3 * RING + idx) * SLOT;
      float4 v4 = *(const float4*)&sR[a + 4 * cl];
      float  v5 = sR[a + 32 + cl];
      #pragma unroll
      for (int j = 0; j < 8; ++j) {
        int kk = rrr - j;
        if (kk >= 0 && kk < 11) {
          float w = wt[kk];
          mu1[j] = fmaf(w, v4.x, mu1[j]);
          mu2[j] = fmaf(w, v4.y, mu2[j]);
          e11[j] = fmaf(w, v4.z, e11[j]);
          e22[j] = fmaf(w, v4.w, e22[j]);
          e12[j] = fmaf(w, v5,  e12[j]);
        }
      }
    }

    #pragma unroll
    for (int j = 0; j < 8; ++j) {
      float m1 = mu1[j], m2 = mu2[j];
      float m1s = m1 * m1, m2s = m2 * m2, m12 = m1 * m2;
      float s11 = e11[j] - m1s, s22 = e22[j] - m2s, s12 = e12[j] - m12;
      float num = (2.f * m12 + C1c) * (2.f * s12 + C2c);
      float den = (m1s + m2s + C1c) * (s11 + s22 + C2c);
      lsum += (1.f - num * __builtin_amdgcn_rcpf(den)) * 0.5f;
    }
    __syncthreads();

    if (k < NCHUNK - 1) {
      // h-compute next chunk's 64 new rows from the prefetched registers
      int r = RB * (k + 1) + 5 + dr;
      bool valid = (unsigned)r < (unsigned)IMG;
      hcompute(A, B, valid, xg, (r + 5) % RING);
      // issue loads for chunk k+2 (complete during next v-phase + barrier)
      if (k < NCHUNK - 2) {
        int rn = RB * (k + 2) + 5 + dr;
        if ((unsigned)rn < (unsigned)IMG) {
          loadrow(p1, rn, cbf, intf, A);
          loadrow(p2, rn, cbf, intf, B);
        }
      }
      __syncthreads();
    }
  }

  // wave-level reduce, one atomic per wave
  #pragma unroll
  for (int off = 32; off > 0; off >>= 1) lsum += __shfl_down(lsum, off);
  if ((tid & 63) == 0) atomicAdd(ws, lsum);
}

extern "C" void kernel_launch(void* const* d_in, const int* in_sizes, int n_in,
                              void* d_out, int out_size, void* d_ws, size_t ws_size,
                              hipStream_t stream) {
  const float* im1 = (const float*)d_in[0];
  const float* im2 = (const float*)d_in[1];
  const float* gk  = (const float*)d_in[2];
  float* out = (float*)d_out;
  float* ws  = (float*)d_ws;

  hipLaunchKernelGGL(dssim_zero, dim3(1), dim3(1), 0, stream, ws);
  hipLaunchKernelGGL(dssim_main, dim3(NIMG * CTILES), dim3(256), 0, stream,
                     im1, im2, gk, ws);
  hipLaunchKernelGGL(dssim_final, dim3(1), dim3(1), 0, stream, ws, out);
}

// Round 5
// 293.012 us; speedup vs baseline: 2.4310x; 2.4310x over previous
//
#include <hip/hip_runtime.h>
#include <math.h>

// DSSIM (mean), B=32 C=3 H=W=512 fp32, separable 11x11 Gaussian.
// R4 = R2 structure (sliding ring, 161 us, no scratch) + packed-FP32 math.
//  - v_pk_fma_f32: process output pairs (2jp, 2jp+1); weight pair
//    wp[m] = {wt[m], wt[m-1]} (zero-padded), data broadcast. 48 packed FMA
//    per plane vs 88 scalar -> h+v FMA instrs 880 -> 480 per thread-chunk.
//  - NO lambdas/helpers: R3 showed un-inlined lambdas demote their array
//    args to scratch (WRITE_SIZE 192 B -> 1.37 GB, 161 -> 586 us).
//  - Ring LDS 74 rows x 4 xg x 44 floats = 52 KB, 3 blocks/CU; each raw row
//    read from global exactly once per strip; SSIM divide via v_rcp_f32.

namespace {
constexpr int IMG = 512;
constexpr int TW = 32;                 // strip width
constexpr int RB = 64;                 // output rows per chunk
constexpr int RING = RB + 10;          // 74 ring rows
constexpr int SLOT = 44;               // floats per (xg, ringrow) slot
constexpr int XGN = TW / 8;            // 4 col-groups
constexpr int NCHUNK = IMG / RB;       // 8
constexpr int CTILES = IMG / TW;       // 16 strips per image
constexpr int NIMG = 96;               // 32*3
constexpr float C1c = 1e-4f;
constexpr float C2c = 9e-4f;
constexpr float INV_N = 1.0f / 25165824.0f;  // 1/(96*512*512)
}

typedef float v2f __attribute__((ext_vector_type(2)));

__global__ void dssim_zero(float* ws) { ws[0] = 0.0f; }

__global__ void dssim_final(const float* __restrict__ ws, float* __restrict__ out) {
  out[0] = ws[0] * INV_N;
}

__global__ __launch_bounds__(256, 3) void dssim_main(
    const float* __restrict__ im1, const float* __restrict__ im2,
    const float* __restrict__ gk, float* __restrict__ ws)
{
  __shared__ float sR[XGN * RING * SLOT];   // 52,096 B

  const int tid = threadIdx.x;
  const int bid = blockIdx.x;
  const int img = bid >> 4;
  const int tsx = bid & 15;
  const int X0s = tsx * TW;

  const float* __restrict__ p1 = im1 + (size_t)img * (IMG * IMG);
  const float* __restrict__ p2 = im2 + (size_t)img * (IMG * IMG);

  // k1[i] = k2d[i][5] / sqrt(k2d[5][5])  (separable, sum(k1)=1)
  float wt[11];
  {
    float ic = 1.0f / sqrtf(gk[5 * 11 + 5]);
    #pragma unroll
    for (int i = 0; i < 11; ++i) wt[i] = gk[i * 11 + 5] * ic;
  }
  // packed weight pairs: wp[m] = {wte(m), wte(m-1)}, wte zero-padded
  v2f wp[12];
  #pragma unroll
  for (int m = 0; m < 12; ++m) {
    float lo = (m <= 10) ? wt[m] : 0.f;
    float hi = (m >= 1) ? wt[m - 1] : 0.f;
    wp[m].x = lo; wp[m].y = hi;
  }

  // v-phase mapping
  const int c   = tid & 31;
  const int yg  = tid >> 5;
  const int xg3 = c >> 3;
  const int cl  = c & 7;

  float lsum = 0.f;

  for (int k = 0; k < NCHUNK; ++k) {
    // ---- h-phase: produce new h-rows into the ring ----
    const int r0    = (k == 0) ? -5 : RB * k + 5;
    const int ntask = (k == 0) ? XGN * RING : XGN * RB;
    for (int t = tid; t < ntask; t += 256) {
      const int xg = t & 3, dr = t >> 2;
      const int r  = r0 + dr;
      const int rr = (r + 5) % RING;      // ring slot row
      const int cb = X0s + xg * 8 - 8;

      float a24[24], b24[24];
      if ((unsigned)r < (unsigned)IMG) {
        const float* row1 = p1 + r * IMG;
        const float* row2 = p2 + r * IMG;
        if (cb >= 0 && cb + 24 <= IMG) {
          #pragma unroll
          for (int i = 0; i < 6; ++i) {
            float4 v1 = *(const float4*)(row1 + cb + 4 * i);
            float4 v2 = *(const float4*)(row2 + cb + 4 * i);
            a24[4*i+0] = v1.x; a24[4*i+1] = v1.y; a24[4*i+2] = v1.z; a24[4*i+3] = v1.w;
            b24[4*i+0] = v2.x; b24[4*i+1] = v2.y; b24[4*i+2] = v2.z; b24[4*i+3] = v2.w;
          }
        } else {
          #pragma unroll
          for (int e = 0; e < 24; ++e) {
            int cc = cb + e;
            bool ok = (unsigned)cc < (unsigned)IMG;
            a24[e] = ok ? row1[cc] : 0.f;
            b24[e] = ok ? row2[cc] : 0.f;
          }
        }
      } else {
        #pragma unroll
        for (int e = 0; e < 24; ++e) { a24[e] = 0.f; b24[e] = 0.f; }
      }

      v2f o0[4], o1[4], o2[4], o3[4], o4[4];
      #pragma unroll
      for (int jp = 0; jp < 4; ++jp) {
        o0[jp] = 0.f; o1[jp] = 0.f; o2[jp] = 0.f; o3[jp] = 0.f; o4[jp] = 0.f;
      }
      #pragma unroll
      for (int e = 0; e < 18; ++e) {
        float va = a24[e + 3], vb = b24[e + 3];
        float pa = va * va, pb = vb * vb, pab = va * vb;
        v2f va2; va2.x = va; va2.y = va;
        v2f vb2; vb2.x = vb; vb2.y = vb;
        v2f pa2; pa2.x = pa; pa2.y = pa;
        v2f pb2; pb2.x = pb; pb2.y = pb;
        v2f pc2; pc2.x = pab; pc2.y = pab;
        #pragma unroll
        for (int jp = 0; jp < 4; ++jp) {
          int m = e - 2 * jp;
          if (m >= 0 && m < 12) {
            v2f w = wp[m];
            o0[jp] = __builtin_elementwise_fma(w, va2, o0[jp]);
            o1[jp] = __builtin_elementwise_fma(w, vb2, o1[jp]);
            o2[jp] = __builtin_elementwise_fma(w, pa2, o2[jp]);
            o3[jp] = __builtin_elementwise_fma(w, pb2, o3[jp]);
            o4[jp] = __builtin_elementwise_fma(w, pc2, o4[jp]);
          }
        }
      }

      const int base = (xg * RING + rr) * SLOT;
      #pragma unroll
      for (int jp = 0; jp < 4; ++jp) {
        *(float4*)&sR[base + 8 * jp]     = make_float4(o0[jp].x, o1[jp].x, o2[jp].x, o3[jp].x);
        *(float4*)&sR[base + 8 * jp + 4] = make_float4(o0[jp].y, o1[jp].y, o2[jp].y, o3[jp].y);
      }
      *(float4*)&sR[base + 32] = make_float4(o4[0].x, o4[0].y, o4[1].x, o4[1].y);
      *(float4*)&sR[base + 36] = make_float4(o4[2].x, o4[2].y, o4[3].x, o4[3].y);
    }
    __syncthreads();

    // ---- v-phase: 8 output rows per thread (4 packed pairs) + SSIM ----
    v2f m1p[4], m2p[4], e11p[4], e22p[4], e12p[4];
    #pragma unroll
    for (int jp = 0; jp < 4; ++jp) {
      m1p[jp] = 0.f; m2p[jp] = 0.f; e11p[jp] = 0.f; e22p[jp] = 0.f; e12p[jp] = 0.f;
    }

    const int rbase = (RB * k + yg * 8) % RING;
    #pragma unroll
    for (int rr = 0; rr < 18; ++rr) {
      int idx = rbase + rr;
      if (idx >= RING) idx -= RING;
      const int a = (xg3 * RING + idx) * SLOT;
      float4 v4 = *(const float4*)&sR[a + 4 * cl];
      float  v5 = sR[a + 32 + cl];
      v2f x1; x1.x = v4.x; x1.y = v4.x;
      v2f x2; x2.x = v4.y; x2.y = v4.y;
      v2f x3; x3.x = v4.z; x3.y = v4.z;
      v2f x4; x4.x = v4.w; x4.y = v4.w;
      v2f x5; x5.x = v5;   x5.y = v5;
      #pragma unroll
      for (int jp = 0; jp < 4; ++jp) {
        int m = rr - 2 * jp;
        if (m >= 0 && m < 12) {
          v2f w = wp[m];
          m1p[jp]  = __builtin_elementwise_fma(w, x1, m1p[jp]);
          m2p[jp]  = __builtin_elementwise_fma(w, x2, m2p[jp]);
          e11p[jp] = __builtin_elementwise_fma(w, x3, e11p[jp]);
          e22p[jp] = __builtin_elementwise_fma(w, x4, e22p[jp]);
          e12p[jp] = __builtin_elementwise_fma(w, x5, e12p[jp]);
        }
      }
    }

    #pragma unroll
    for (int jp = 0; jp < 4; ++jp) {
      v2f m1 = m1p[jp], m2 = m2p[jp];
      v2f m1s = m1 * m1, m2s = m2 * m2, m12 = m1 * m2;
      v2f s11 = e11p[jp] - m1s, s22 = e22p[jp] - m2s, s12 = e12p[jp] - m12;
      v2f num = (2.f * m12 + C1c) * (2.f * s12 + C2c);
      v2f den = (m1s + m2s + C1c) * (s11 + s22 + C2c);
      lsum += (1.f - num.x * __builtin_amdgcn_rcpf(den.x)) * 0.5f;
      lsum += (1.f - num.y * __builtin_amdgcn_rcpf(den.y)) * 0.5f;
    }
    __syncthreads();
  }

  // wave-level reduce, one atomic per wave
  #pragma unroll
  for (int off = 32; off > 0; off >>= 1) lsum += __shfl_down(lsum, off);
  if ((tid & 63) == 0) atomicAdd(ws, lsum);
}

extern "C" void kernel_launch(void* const* d_in, const int* in_sizes, int n_in,
                              void* d_out, int out_size, void* d_ws, size_t ws_size,
                              hipStream_t stream) {
  const float* im1 = (const float*)d_in[0];
  const float* im2 = (const float*)d_in[1];
  const float* gk  = (const float*)d_in[2];
  float* out = (float*)d_out;
  float* ws  = (float*)d_ws;

  hipLaunchKernelGGL(dssim_zero, dim3(1), dim3(1), 0, stream, ws);
  hipLaunchKernelGGL(dssim_main, dim3(NIMG * CTILES), dim3(256), 0, stream,
                     im1, im2, gk, ws);
  hipLaunchKernelGGL(dssim_final, dim3(1), dim3(1), 0, stream, ws, out);
}